// Round 1
// baseline (634.396 us; speedup 1.0000x reference)
//
#include <hip/hip_runtime.h>
#include <hip/hip_bf16.h>

typedef __attribute__((ext_vector_type(8))) short short8;
typedef __attribute__((ext_vector_type(4))) float f32x4;

#define S_LEN 2048
#define DM 1024
#define NH 16
#define HD 64
#define PD 64

// ---------------------------------------------------------------------------
// prep kernels
// ---------------------------------------------------------------------------

__global__ void convx_kernel(const float* __restrict__ x,
                             __hip_bfloat16* __restrict__ xb, int n4) {
  int i = blockIdx.x * blockDim.x + threadIdx.x;
  if (i >= n4) return;
  const float4 v = reinterpret_cast<const float4*>(x)[i];
  union { __hip_bfloat16 h[4]; ushort4 u; } o;
  o.h[0] = __float2bfloat16(v.x);
  o.h[1] = __float2bfloat16(v.y);
  o.h[2] = __float2bfloat16(v.z);
  o.h[3] = __float2bfloat16(v.w);
  reinterpret_cast<ushort4*>(xb)[i] = o.u;
}

// one wave per position row: bf16 copy + f32 squared norm
__global__ void posprep_kernel(const float* __restrict__ pos,
                               __hip_bfloat16* __restrict__ posb,
                               float* __restrict__ pnorm) {
  int row = blockIdx.x, c = threadIdx.x;
  float v = pos[row * PD + c];
  posb[row * PD + c] = __float2bfloat16(v);
  float s = v * v;
#pragma unroll
  for (int m = 1; m < 64; m <<= 1) s += __shfl_xor(s, m);
  if (c == 0) pnorm[row] = s;
}

// W [K][N] f32 -> Wt [N][K] bf16, 32x32 LDS tile transpose; blockIdx.z picks matrix
__global__ __launch_bounds__(256) void wtrans_kernel(
    const float* __restrict__ W0, const float* __restrict__ W1,
    const float* __restrict__ W2, const float* __restrict__ W3,
    __hip_bfloat16* __restrict__ T0, __hip_bfloat16* __restrict__ T1,
    __hip_bfloat16* __restrict__ T2, __hip_bfloat16* __restrict__ T3) {
  __shared__ float tile[32][33];
  const float* W = blockIdx.z == 0 ? W0 : blockIdx.z == 1 ? W1
                 : blockIdx.z == 2 ? W2 : W3;
  __hip_bfloat16* T = blockIdx.z == 0 ? T0 : blockIdx.z == 1 ? T1
                    : blockIdx.z == 2 ? T2 : T3;
  int tx = threadIdx.x & 31, ty = threadIdx.x >> 5;  // tx 0..31, ty 0..7
  int k0 = blockIdx.x * 32, n0 = blockIdx.y * 32;
#pragma unroll
  for (int q = 0; q < 4; ++q)
    tile[ty + q * 8][tx] = W[(size_t)(k0 + ty + q * 8) * DM + n0 + tx];
  __syncthreads();
#pragma unroll
  for (int q = 0; q < 4; ++q)
    T[(size_t)(n0 + ty + q * 8) * DM + k0 + tx] =
        __float2bfloat16(tile[tx][ty + q * 8]);
}

// ---------------------------------------------------------------------------
// GEMM: C[m][n] = sum_k A[m][k] * Bt[n][k] + bias[n]
// Fragment layouts (mfma_f32_16x16x32_bf16):
//   a_frag lane l elem i : A[l&15][(l>>4)*8 + i]   (contiguous 16B)
//   b_frag lane l elem i : Bt[l&15][(l>>4)*8 + i]  (contiguous 16B)
//   d      lane l reg  r : C[(l>>4)*4 + r][l&15]
// Tile 128x64, 4 waves in 2x2, each wave 64x32 (4x2 fragments). Direct-global
// fragment loads (no LDS staging) — L2 feeds the reuse.
// mode 0: bf16 out [B,H,S,64] (Q,K)   mode 1: bf16 out [B,H,64,S] (V^T)
// mode 2: f32 out row-major [M][N]
// ---------------------------------------------------------------------------
__global__ __launch_bounds__(256) void gemm_bt_kernel(
    const __hip_bfloat16* __restrict__ A, const __hip_bfloat16* __restrict__ Bt,
    const float* __restrict__ bias, void* __restrict__ out,
    int M, int N, int K, int mode) {
  int tid = threadIdx.x;
  int lane = tid & 63, wid = tid >> 6;
  int lr = lane & 15, lh = lane >> 4;
  int wr = wid >> 1, wc = wid & 1;
  int m0 = blockIdx.x * 128 + wr * 64;
  int n0 = blockIdx.y * 64 + wc * 32;

  f32x4 acc[4][2];
#pragma unroll
  for (int mi = 0; mi < 4; ++mi)
#pragma unroll
    for (int ni = 0; ni < 2; ++ni) acc[mi][ni] = (f32x4){0.f, 0.f, 0.f, 0.f};

  const __hip_bfloat16* Ap = A + (size_t)(m0 + lr) * K + lh * 8;
  const __hip_bfloat16* Bp = Bt + (size_t)(n0 + lr) * K + lh * 8;

  for (int k0 = 0; k0 < K; k0 += 32) {
    short8 a[4], b[2];
#pragma unroll
    for (int mi = 0; mi < 4; ++mi)
      a[mi] = *reinterpret_cast<const short8*>(Ap + (size_t)mi * 16 * K + k0);
#pragma unroll
    for (int ni = 0; ni < 2; ++ni)
      b[ni] = *reinterpret_cast<const short8*>(Bp + (size_t)ni * 16 * K + k0);
#pragma unroll
    for (int mi = 0; mi < 4; ++mi)
#pragma unroll
      for (int ni = 0; ni < 2; ++ni)
        acc[mi][ni] = __builtin_amdgcn_mfma_f32_16x16x32_bf16(
            a[mi], b[ni], acc[mi][ni], 0, 0, 0);
  }

#pragma unroll
  for (int mi = 0; mi < 4; ++mi)
#pragma unroll
    for (int ni = 0; ni < 2; ++ni)
#pragma unroll
      for (int r = 0; r < 4; ++r) {
        int row = m0 + mi * 16 + lh * 4 + r;
        int col = n0 + ni * 16 + lr;
        float v = acc[mi][ni][r] + bias[col];
        if (mode == 2) {
          reinterpret_cast<float*>(out)[(size_t)row * N + col] = v;
        } else {
          int bb = row >> 11, s = row & 2047, h = col >> 6, d = col & 63;
          size_t idx = (mode == 0)
                           ? ((size_t)(bb * NH + h) * S_LEN + s) * HD + d
                           : ((size_t)(bb * NH + h) * HD + d) * S_LEN + s;
          reinterpret_cast<__hip_bfloat16*>(out)[idx] = __float2bfloat16(v);
        }
      }
}

// ---------------------------------------------------------------------------
// Flash attention with geodesic-distance bias.
// scores_ij = (q_i . k_j)/8 - dist(i,j);  dist = sqrt(ni + nj - 2*p_i.p_j),
// dist(i,i) forced to exactly 0 (matches reference; critical for accuracy).
// Block = 4 waves; each wave owns 16 q-rows, iterates j in chunks of 32.
// ---------------------------------------------------------------------------
__global__ __launch_bounds__(256) void attn_kernel(
    const __hip_bfloat16* __restrict__ qb, const __hip_bfloat16* __restrict__ kb,
    const __hip_bfloat16* __restrict__ vt, const __hip_bfloat16* __restrict__ posb,
    const float* __restrict__ pnorm, __hip_bfloat16* __restrict__ ob) {
  __shared__ __hip_bfloat16 plds[4][16 * 32];
  int tid = threadIdx.x;
  int lane = tid & 63, w = tid >> 6;
  int lr = lane & 15, lh = lane >> 4;
  int bh = blockIdx.y;
  int b = bh >> 4, h = bh & 15;
  int s0 = blockIdx.x * 64 + w * 16;

  const __hip_bfloat16* qh = qb + (size_t)bh * S_LEN * HD;
  const __hip_bfloat16* kh = kb + (size_t)bh * S_LEN * HD;
  const __hip_bfloat16* vh = vt + (size_t)bh * HD * S_LEN;

  short8 qf[2], pf[2];
  qf[0] = *reinterpret_cast<const short8*>(qh + (size_t)(s0 + lr) * HD + lh * 8);
  qf[1] = *reinterpret_cast<const short8*>(qh + (size_t)(s0 + lr) * HD + 32 + lh * 8);
  pf[0] = *reinterpret_cast<const short8*>(posb + (size_t)(s0 + lr) * PD + lh * 8);
  pf[1] = *reinterpret_cast<const short8*>(posb + (size_t)(s0 + lr) * PD + 32 + lh * 8);

  float ni[4];
#pragma unroll
  for (int r = 0; r < 4; ++r) ni[r] = pnorm[s0 + lh * 4 + r];

  f32x4 accO[4];
#pragma unroll
  for (int n = 0; n < 4; ++n) accO[n] = (f32x4){0.f, 0.f, 0.f, 0.f};
  float mst[4], lst[4];
#pragma unroll
  for (int r = 0; r < 4; ++r) { mst[r] = -1e30f; lst[r] = 0.f; }

  const f32x4 z4 = (f32x4){0.f, 0.f, 0.f, 0.f};

  for (int j0 = 0; j0 < S_LEN; j0 += 32) {
    float sc[2][4];
#pragma unroll
    for (int jt = 0; jt < 2; ++jt) {
      int jb = j0 + jt * 16;
      short8 kf0 = *reinterpret_cast<const short8*>(kh + (size_t)(jb + lr) * HD + lh * 8);
      short8 kf1 = *reinterpret_cast<const short8*>(kh + (size_t)(jb + lr) * HD + 32 + lh * 8);
      f32x4 s4 = __builtin_amdgcn_mfma_f32_16x16x32_bf16(qf[0], kf0, z4, 0, 0, 0);
      s4 = __builtin_amdgcn_mfma_f32_16x16x32_bf16(qf[1], kf1, s4, 0, 0, 0);
      short8 pb0 = *reinterpret_cast<const short8*>(posb + (size_t)(jb + lr) * PD + lh * 8);
      short8 pb1 = *reinterpret_cast<const short8*>(posb + (size_t)(jb + lr) * PD + 32 + lh * 8);
      f32x4 g4 = __builtin_amdgcn_mfma_f32_16x16x32_bf16(pf[0], pb0, z4, 0, 0, 0);
      g4 = __builtin_amdgcn_mfma_f32_16x16x32_bf16(pf[1], pb1, g4, 0, 0, 0);
      float nj = pnorm[jb + lr];
#pragma unroll
      for (int r = 0; r < 4; ++r) {
        int ig = s0 + lh * 4 + r;
        int jg = jb + lr;
        float d2 = ni[r] + nj - 2.f * g4[r];
        float dist = (ig == jg) ? 0.f : sqrtf(fmaxf(d2, 0.f));
        sc[jt][r] = s4[r] * 0.125f - dist;
      }
    }
    // online softmax (rows live in 16-lane groups; reduce with shfl_xor 1,2,4,8)
    float ps[2][4];
#pragma unroll
    for (int r = 0; r < 4; ++r) {
      float rm = fmaxf(sc[0][r], sc[1][r]);
#pragma unroll
      for (int m = 1; m < 16; m <<= 1) rm = fmaxf(rm, __shfl_xor(rm, m));
      float nm = fmaxf(mst[r], rm);
      float sscale = __expf(mst[r] - nm);
      ps[0][r] = __expf(sc[0][r] - nm);
      ps[1][r] = __expf(sc[1][r] - nm);
      float rs = ps[0][r] + ps[1][r];
#pragma unroll
      for (int m = 1; m < 16; m <<= 1) rs += __shfl_xor(rs, m);
      lst[r] = lst[r] * sscale + rs;
      mst[r] = nm;
#pragma unroll
      for (int n = 0; n < 4; ++n) accO[n][r] *= sscale;
    }
    // P: D-layout -> A-layout via per-wave LDS tile [16 rows][32 cols]
#pragma unroll
    for (int jt = 0; jt < 2; ++jt)
#pragma unroll
      for (int r = 0; r < 4; ++r)
        plds[w][(lh * 4 + r) * 32 + jt * 16 + lr] = __float2bfloat16(ps[jt][r]);
    short8 pfrag = *reinterpret_cast<const short8*>(&plds[w][lr * 32 + lh * 8]);
#pragma unroll
    for (int n = 0; n < 4; ++n) {
      short8 vf = *reinterpret_cast<const short8*>(
          vh + (size_t)(n * 16 + lr) * S_LEN + j0 + lh * 8);
      accO[n] = __builtin_amdgcn_mfma_f32_16x16x32_bf16(pfrag, vf, accO[n], 0, 0, 0);
    }
  }

  float inv[4];
#pragma unroll
  for (int r = 0; r < 4; ++r) inv[r] = 1.f / lst[r];
#pragma unroll
  for (int n = 0; n < 4; ++n)
#pragma unroll
    for (int r = 0; r < 4; ++r) {
      int s = s0 + lh * 4 + r;
      ob[((size_t)(b * S_LEN) + s) * DM + h * HD + n * 16 + lr] =
          __float2bfloat16(accO[n][r] * inv[r]);
    }
}

// ---------------------------------------------------------------------------
// launch
// ---------------------------------------------------------------------------
extern "C" void kernel_launch(void* const* d_in, const int* in_sizes, int n_in,
                              void* d_out, int out_size, void* d_ws, size_t ws_size,
                              hipStream_t stream) {
  const float* x   = (const float*)d_in[0];
  const float* pos = (const float*)d_in[1];
  const float* Wq  = (const float*)d_in[2];
  const float* bq  = (const float*)d_in[3];
  const float* Wk  = (const float*)d_in[4];
  const float* bk  = (const float*)d_in[5];
  const float* Wv  = (const float*)d_in[6];
  const float* bv  = (const float*)d_in[7];
  const float* Wo  = (const float*)d_in[8];
  const float* bo  = (const float*)d_in[9];

  char* ws = (char*)d_ws;
  size_t off = 0;
  auto alloc = [&](size_t bytes) {
    char* p = ws + off;
    off += (bytes + 255) & ~(size_t)255;
    return p;
  };
  __hip_bfloat16* xb   = (__hip_bfloat16*)alloc((size_t)4096 * DM * 2);   // 8 MB
  __hip_bfloat16* wqT  = (__hip_bfloat16*)alloc((size_t)DM * DM * 2);     // 2 MB
  __hip_bfloat16* wkT  = (__hip_bfloat16*)alloc((size_t)DM * DM * 2);
  __hip_bfloat16* wvT  = (__hip_bfloat16*)alloc((size_t)DM * DM * 2);
  __hip_bfloat16* woT  = (__hip_bfloat16*)alloc((size_t)DM * DM * 2);
  __hip_bfloat16* posb = (__hip_bfloat16*)alloc((size_t)S_LEN * PD * 2);
  float*          pnrm = (float*)alloc((size_t)S_LEN * 4);
  __hip_bfloat16* qb   = (__hip_bfloat16*)alloc((size_t)2 * NH * S_LEN * HD * 2); // 8 MB
  __hip_bfloat16* kb   = (__hip_bfloat16*)alloc((size_t)2 * NH * S_LEN * HD * 2);
  __hip_bfloat16* vt   = (__hip_bfloat16*)alloc((size_t)2 * NH * S_LEN * HD * 2);
  __hip_bfloat16* ob   = (__hip_bfloat16*)alloc((size_t)4096 * DM * 2);   // 8 MB
  (void)ws_size;

  // prep
  int n4 = 4096 * DM / 4;
  hipLaunchKernelGGL(convx_kernel, dim3((n4 + 255) / 256), dim3(256), 0, stream,
                     x, xb, n4);
  hipLaunchKernelGGL(posprep_kernel, dim3(S_LEN), dim3(64), 0, stream,
                     pos, posb, pnrm);
  hipLaunchKernelGGL(wtrans_kernel, dim3(32, 32, 4), dim3(256), 0, stream,
                     Wq, Wk, Wv, Wo, wqT, wkT, wvT, woT);

  // QKV projections (M=4096, N=1024, K=1024)
  dim3 ggrid(4096 / 128, DM / 64);
  hipLaunchKernelGGL(gemm_bt_kernel, ggrid, dim3(256), 0, stream,
                     xb, wqT, bq, (void*)qb, 4096, DM, DM, 0);
  hipLaunchKernelGGL(gemm_bt_kernel, ggrid, dim3(256), 0, stream,
                     xb, wkT, bk, (void*)kb, 4096, DM, DM, 0);
  hipLaunchKernelGGL(gemm_bt_kernel, ggrid, dim3(256), 0, stream,
                     xb, wvT, bv, (void*)vt, 4096, DM, DM, 1);

  // attention
  hipLaunchKernelGGL(attn_kernel, dim3(S_LEN / 64, 2 * NH), dim3(256), 0, stream,
                     qb, kb, vt, posb, pnrm, ob);

  // output projection -> f32 d_out
  hipLaunchKernelGGL(gemm_bt_kernel, ggrid, dim3(256), 0, stream,
                     ob, woT, bo, d_out, 4096, DM, DM, 2);
}

// Round 3
// 531.017 us; speedup vs baseline: 1.1947x; 1.1947x over previous
//
#include <hip/hip_runtime.h>
#include <hip/hip_bf16.h>

typedef __attribute__((ext_vector_type(8))) short short8;
typedef __attribute__((ext_vector_type(4))) float f32x4;

#define S_LEN 2048
#define DM 1024
#define NH 16
#define HD 64
#define PD 64

#define LOG2E 1.4426950408889634f

#if __has_builtin(__builtin_amdgcn_exp2f)
#define EXP2F(x) __builtin_amdgcn_exp2f(x)
#else
#define EXP2F(x) exp2f(x)
#endif

static __device__ inline float bf2f(unsigned short u) {
  union { unsigned int i; float f; } c;
  c.i = ((unsigned int)u) << 16;
  return c.f;
}
static __device__ inline unsigned short f2bf(float f) {
  __hip_bfloat16 h = __float2bfloat16(f);
  return *reinterpret_cast<unsigned short*>(&h);
}

// ---------------------------------------------------------------------------
// prep kernels
// ---------------------------------------------------------------------------

__global__ void convx_kernel(const float* __restrict__ x,
                             __hip_bfloat16* __restrict__ xb, int n4) {
  int i = blockIdx.x * blockDim.x + threadIdx.x;
  if (i >= n4) return;
  const float4 v = reinterpret_cast<const float4*>(x)[i];
  union { __hip_bfloat16 h[4]; ushort4 u; } o;
  o.h[0] = __float2bfloat16(v.x);
  o.h[1] = __float2bfloat16(v.y);
  o.h[2] = __float2bfloat16(v.z);
  o.h[3] = __float2bfloat16(v.w);
  reinterpret_cast<ushort4*>(xb)[i] = o.u;
}

// one wave per position row: bf16 copy + f32 squared norm
__global__ void posprep_kernel(const float* __restrict__ pos,
                               __hip_bfloat16* __restrict__ posb,
                               float* __restrict__ pnorm) {
  int row = blockIdx.x, c = threadIdx.x;
  float v = pos[row * PD + c];
  posb[row * PD + c] = __float2bfloat16(v);
  float s = v * v;
#pragma unroll
  for (int m = 1; m < 64; m <<= 1) s += __shfl_xor(s, m);
  if (c == 0) pnorm[row] = s;
}

// W [K][N] f32 -> Wt [N][K] bf16, 32x32 LDS tile transpose; blockIdx.z picks matrix
__global__ __launch_bounds__(256) void wtrans_kernel(
    const float* __restrict__ W0, const float* __restrict__ W1,
    const float* __restrict__ W2, const float* __restrict__ W3,
    __hip_bfloat16* __restrict__ T0, __hip_bfloat16* __restrict__ T1,
    __hip_bfloat16* __restrict__ T2, __hip_bfloat16* __restrict__ T3) {
  __shared__ float tile[32][33];
  const float* W = blockIdx.z == 0 ? W0 : blockIdx.z == 1 ? W1
                 : blockIdx.z == 2 ? W2 : W3;
  __hip_bfloat16* T = blockIdx.z == 0 ? T0 : blockIdx.z == 1 ? T1
                    : blockIdx.z == 2 ? T2 : T3;
  int tx = threadIdx.x & 31, ty = threadIdx.x >> 5;  // tx 0..31, ty 0..7
  int k0 = blockIdx.x * 32, n0 = blockIdx.y * 32;
#pragma unroll
  for (int q = 0; q < 4; ++q)
    tile[ty + q * 8][tx] = W[(size_t)(k0 + ty + q * 8) * DM + n0 + tx];
  __syncthreads();
#pragma unroll
  for (int q = 0; q < 4; ++q)
    T[(size_t)(n0 + ty + q * 8) * DM + k0 + tx] =
        __float2bfloat16(tile[tx][ty + q * 8]);
}

// ---------------------------------------------------------------------------
// Distance-bias precompute: Dt[qt][j][ii] = -dist(qt*16+ii, j) * log2e (bf16),
// dist(i,i) = 0 exactly. Gram via MFMA; tiled layout matches attn's D-layout
// fragment (lane (lh,lr) reads ushort4 at [(qt*2048+j)*16 + lh*4]).
// Block 128x64, 4 waves 2x2, each wave 64x32. K = PD = 64 (2 k-steps).
// ---------------------------------------------------------------------------
__global__ __launch_bounds__(256) void dmt_kernel(
    const __hip_bfloat16* __restrict__ posb, const float* __restrict__ pnorm,
    __hip_bfloat16* __restrict__ dtout) {
  int tid = threadIdx.x;
  int lane = tid & 63, wid = tid >> 6;
  int lr = lane & 15, lh = lane >> 4;
  int wr = wid >> 1, wc = wid & 1;
  int m0 = blockIdx.x * 128 + wr * 64;
  int n0 = blockIdx.y * 64 + wc * 32;

  f32x4 acc[4][2];
#pragma unroll
  for (int mi = 0; mi < 4; ++mi)
#pragma unroll
    for (int ni = 0; ni < 2; ++ni) acc[mi][ni] = (f32x4){0.f, 0.f, 0.f, 0.f};

  const __hip_bfloat16* Ap = posb + (size_t)(m0 + lr) * PD + lh * 8;
  const __hip_bfloat16* Bp = posb + (size_t)(n0 + lr) * PD + lh * 8;

#pragma unroll
  for (int k0 = 0; k0 < PD; k0 += 32) {
    short8 a[4], b[2];
#pragma unroll
    for (int mi = 0; mi < 4; ++mi)
      a[mi] = *reinterpret_cast<const short8*>(Ap + (size_t)mi * 16 * PD + k0);
#pragma unroll
    for (int ni = 0; ni < 2; ++ni)
      b[ni] = *reinterpret_cast<const short8*>(Bp + (size_t)ni * 16 * PD + k0);
#pragma unroll
    for (int mi = 0; mi < 4; ++mi)
#pragma unroll
      for (int ni = 0; ni < 2; ++ni)
        acc[mi][ni] = __builtin_amdgcn_mfma_f32_16x16x32_bf16(
            a[mi], b[ni], acc[mi][ni], 0, 0, 0);
  }

#pragma unroll
  for (int mi = 0; mi < 4; ++mi) {
    float nim[4];
#pragma unroll
    for (int r = 0; r < 4; ++r) nim[r] = pnorm[m0 + mi * 16 + lh * 4 + r];
#pragma unroll
    for (int ni = 0; ni < 2; ++ni) {
      int j = n0 + ni * 16 + lr;
      float nj = pnorm[j];
      ushort4 o;
      unsigned short* op = &o.x;
#pragma unroll
      for (int r = 0; r < 4; ++r) {
        int i = m0 + mi * 16 + lh * 4 + r;
        float d2 = nim[r] + nj - 2.f * acc[mi][ni][r];
        float dist = (i == j) ? 0.f : sqrtf(fmaxf(d2, 0.f));
        op[r] = f2bf(-dist * LOG2E);
      }
      int qt = (m0 + mi * 16) >> 4;
      *reinterpret_cast<ushort4*>(dtout + ((size_t)qt * S_LEN + j) * 16 + lh * 4) = o;
    }
  }
}

// ---------------------------------------------------------------------------
// Fused QKV projection: C[m][n] = x[m][:] . WqkvT[n][:] + bias, n in [0,3072).
// n>>10 routes to Q [B,H,S,64], K [B,H,S,64], or V^T [B,H,64,S].
// ---------------------------------------------------------------------------
__global__ __launch_bounds__(256) void gemm_qkv_kernel(
    const __hip_bfloat16* __restrict__ A, const __hip_bfloat16* __restrict__ Bt,
    const float* __restrict__ bq, const float* __restrict__ bk,
    const float* __restrict__ bv, __hip_bfloat16* __restrict__ qb,
    __hip_bfloat16* __restrict__ kb, __hip_bfloat16* __restrict__ vt) {
  const int K = DM;
  int tid = threadIdx.x;
  int lane = tid & 63, wid = tid >> 6;
  int lr = lane & 15, lh = lane >> 4;
  int wr = wid >> 1, wc = wid & 1;
  int m0 = blockIdx.x * 128 + wr * 64;
  int n0 = blockIdx.y * 64 + wc * 32;

  f32x4 acc[4][2];
#pragma unroll
  for (int mi = 0; mi < 4; ++mi)
#pragma unroll
    for (int ni = 0; ni < 2; ++ni) acc[mi][ni] = (f32x4){0.f, 0.f, 0.f, 0.f};

  const __hip_bfloat16* Ap = A + (size_t)(m0 + lr) * K + lh * 8;
  const __hip_bfloat16* Bp = Bt + (size_t)(n0 + lr) * K + lh * 8;

  for (int k0 = 0; k0 < K; k0 += 32) {
    short8 a[4], b[2];
#pragma unroll
    for (int mi = 0; mi < 4; ++mi)
      a[mi] = *reinterpret_cast<const short8*>(Ap + (size_t)mi * 16 * K + k0);
#pragma unroll
    for (int ni = 0; ni < 2; ++ni)
      b[ni] = *reinterpret_cast<const short8*>(Bp + (size_t)ni * 16 * K + k0);
#pragma unroll
    for (int mi = 0; mi < 4; ++mi)
#pragma unroll
      for (int ni = 0; ni < 2; ++ni)
        acc[mi][ni] = __builtin_amdgcn_mfma_f32_16x16x32_bf16(
            a[mi], b[ni], acc[mi][ni], 0, 0, 0);
  }

#pragma unroll
  for (int mi = 0; mi < 4; ++mi)
#pragma unroll
    for (int ni = 0; ni < 2; ++ni)
#pragma unroll
      for (int r = 0; r < 4; ++r) {
        int row = m0 + mi * 16 + lh * 4 + r;
        int col = n0 + ni * 16 + lr;
        int which = col >> 10, within = col & 1023;
        int bb = row >> 11, s = row & 2047;
        int h = within >> 6, d = within & 63;
        const float* bias = which == 0 ? bq : which == 1 ? bk : bv;
        float v = acc[mi][ni][r] + bias[within];
        __hip_bfloat16 hv = __float2bfloat16(v);
        if (which == 0)
          qb[((size_t)(bb * NH + h) * S_LEN + s) * HD + d] = hv;
        else if (which == 1)
          kb[((size_t)(bb * NH + h) * S_LEN + s) * HD + d] = hv;
        else
          vt[((size_t)(bb * NH + h) * HD + d) * S_LEN + s] = hv;
      }
}

// ---------------------------------------------------------------------------
// Output projection: f32 out row-major, A bf16, Bt bf16.
// ---------------------------------------------------------------------------
__global__ __launch_bounds__(256) void gemm_out_kernel(
    const __hip_bfloat16* __restrict__ A, const __hip_bfloat16* __restrict__ Bt,
    const float* __restrict__ bias, float* __restrict__ out) {
  const int K = DM, N = DM;
  int tid = threadIdx.x;
  int lane = tid & 63, wid = tid >> 6;
  int lr = lane & 15, lh = lane >> 4;
  int wr = wid >> 1, wc = wid & 1;
  int m0 = blockIdx.x * 128 + wr * 64;
  int n0 = blockIdx.y * 64 + wc * 32;

  f32x4 acc[4][2];
#pragma unroll
  for (int mi = 0; mi < 4; ++mi)
#pragma unroll
    for (int ni = 0; ni < 2; ++ni) acc[mi][ni] = (f32x4){0.f, 0.f, 0.f, 0.f};

  const __hip_bfloat16* Ap = A + (size_t)(m0 + lr) * K + lh * 8;
  const __hip_bfloat16* Bp = Bt + (size_t)(n0 + lr) * K + lh * 8;

  for (int k0 = 0; k0 < K; k0 += 32) {
    short8 a[4], b[2];
#pragma unroll
    for (int mi = 0; mi < 4; ++mi)
      a[mi] = *reinterpret_cast<const short8*>(Ap + (size_t)mi * 16 * K + k0);
#pragma unroll
    for (int ni = 0; ni < 2; ++ni)
      b[ni] = *reinterpret_cast<const short8*>(Bp + (size_t)ni * 16 * K + k0);
#pragma unroll
    for (int mi = 0; mi < 4; ++mi)
#pragma unroll
      for (int ni = 0; ni < 2; ++ni)
        acc[mi][ni] = __builtin_amdgcn_mfma_f32_16x16x32_bf16(
            a[mi], b[ni], acc[mi][ni], 0, 0, 0);
  }

#pragma unroll
  for (int mi = 0; mi < 4; ++mi)
#pragma unroll
    for (int ni = 0; ni < 2; ++ni)
#pragma unroll
      for (int r = 0; r < 4; ++r) {
        int row = m0 + mi * 16 + lh * 4 + r;
        int col = n0 + ni * 16 + lr;
        out[(size_t)row * N + col] = acc[mi][ni][r] + bias[col];
      }
}

// ---------------------------------------------------------------------------
// Flash attention with precomputed distance bias, no-max softmax.
//   score2(i,j) = (q_i.k_j) * (0.125*log2e) + Dt(i,j)   [Dt = -dist*log2e]
//   p = exp2(score2)  -- bounded, no running max needed
//   denom via ones-MFMA (same bf16-rounded P as numerator)
// Block = 4 waves; each wave owns 16 q-rows, iterates j in chunks of 64.
// P transpose via per-wave XOR-swizzled LDS tile [16][64].
// ---------------------------------------------------------------------------
__global__ __launch_bounds__(256) void attn_kernel(
    const __hip_bfloat16* __restrict__ qb, const __hip_bfloat16* __restrict__ kb,
    const __hip_bfloat16* __restrict__ vt, const __hip_bfloat16* __restrict__ dt,
    __hip_bfloat16* __restrict__ ob) {
  __shared__ __hip_bfloat16 plds[4][16 * 64];
  int tid = threadIdx.x;
  int lane = tid & 63, w = tid >> 6;
  int lr = lane & 15, lh = lane >> 4;
  int bh = blockIdx.y;
  int b = bh >> 4, h = bh & 15;
  int s0 = blockIdx.x * 64 + w * 16;
  int qt = s0 >> 4;

  const __hip_bfloat16* qh = qb + (size_t)bh * S_LEN * HD;
  const __hip_bfloat16* kh = kb + (size_t)bh * S_LEN * HD;
  const __hip_bfloat16* vh = vt + (size_t)bh * HD * S_LEN;

  short8 qf0 = *reinterpret_cast<const short8*>(qh + (size_t)(s0 + lr) * HD + lh * 8);
  short8 qf1 = *reinterpret_cast<const short8*>(qh + (size_t)(s0 + lr) * HD + 32 + lh * 8);

  f32x4 accO[4];
#pragma unroll
  for (int n = 0; n < 4; ++n) accO[n] = (f32x4){0.f, 0.f, 0.f, 0.f};
  f32x4 lacc = (f32x4){0.f, 0.f, 0.f, 0.f};

  short8 ones;
#pragma unroll
  for (int e = 0; e < 8; ++e) ones[e] = (short)0x3F80;  // bf16 1.0

  const f32x4 z4 = (f32x4){0.f, 0.f, 0.f, 0.f};
  const float C2 = 0.125f * LOG2E;

  for (int j0 = 0; j0 < S_LEN; j0 += 64) {
#pragma unroll
    for (int jt = 0; jt < 4; ++jt) {
      int jb = j0 + jt * 16;
      short8 kf0 = *reinterpret_cast<const short8*>(kh + (size_t)(jb + lr) * HD + lh * 8);
      short8 kf1 = *reinterpret_cast<const short8*>(kh + (size_t)(jb + lr) * HD + 32 + lh * 8);
      f32x4 s4 = __builtin_amdgcn_mfma_f32_16x16x32_bf16(qf0, kf0, z4, 0, 0, 0);
      s4 = __builtin_amdgcn_mfma_f32_16x16x32_bf16(qf1, kf1, s4, 0, 0, 0);
      ushort4 dv = *reinterpret_cast<const ushort4*>(
          dt + ((size_t)qt * S_LEN + jb + lr) * 16 + lh * 4);
      const unsigned short* dp = &dv.x;
#pragma unroll
      for (int r = 0; r < 4; ++r) {
        float score2 = s4[r] * C2 + bf2f(dp[r]);
        float p = EXP2F(score2);
        int row = lh * 4 + r;
        int c = jt * 16 + lr;
        // XOR-swizzled store: 8-col block index ^= (row & 7)
        int idx = row * 64 + (((c >> 3) ^ (row & 7)) << 3) + (c & 7);
        plds[w][idx] = __float2bfloat16(p);
      }
    }
    // per-wave LDS tile, same-wave RAW: compiler inserts lgkmcnt wait
#pragma unroll
    for (int p2 = 0; p2 < 2; ++p2) {
      short8 pfrag = *reinterpret_cast<const short8*>(
          &plds[w][lr * 64 + ((((p2 * 4 + lh)) ^ (lr & 7)) << 3)]);
      lacc = __builtin_amdgcn_mfma_f32_16x16x32_bf16(pfrag, ones, lacc, 0, 0, 0);
#pragma unroll
      for (int n = 0; n < 4; ++n) {
        short8 vf = *reinterpret_cast<const short8*>(
            vh + (size_t)(n * 16 + lr) * S_LEN + j0 + p2 * 32 + lh * 8);
        accO[n] = __builtin_amdgcn_mfma_f32_16x16x32_bf16(pfrag, vf, accO[n], 0, 0, 0);
      }
    }
  }

  float inv[4];
#pragma unroll
  for (int r = 0; r < 4; ++r) inv[r] = 1.f / lacc[r];
#pragma unroll
  for (int n = 0; n < 4; ++n)
#pragma unroll
    for (int r = 0; r < 4; ++r) {
      int s = s0 + lh * 4 + r;
      ob[((size_t)(b * S_LEN) + s) * DM + h * HD + n * 16 + lr] =
          __float2bfloat16(accO[n][r] * inv[r]);
    }
}

// ---------------------------------------------------------------------------
// launch
// ---------------------------------------------------------------------------
extern "C" void kernel_launch(void* const* d_in, const int* in_sizes, int n_in,
                              void* d_out, int out_size, void* d_ws, size_t ws_size,
                              hipStream_t stream) {
  const float* x   = (const float*)d_in[0];
  const float* pos = (const float*)d_in[1];
  const float* Wq  = (const float*)d_in[2];
  const float* bq  = (const float*)d_in[3];
  const float* Wk  = (const float*)d_in[4];
  const float* bk  = (const float*)d_in[5];
  const float* Wv  = (const float*)d_in[6];
  const float* bv  = (const float*)d_in[7];
  const float* Wo  = (const float*)d_in[8];
  const float* bo  = (const float*)d_in[9];

  char* ws = (char*)d_ws;
  size_t off = 0;
  auto alloc = [&](size_t bytes) {
    char* p = ws + off;
    off += (bytes + 255) & ~(size_t)255;
    return p;
  };
  __hip_bfloat16* xb    = (__hip_bfloat16*)alloc((size_t)4096 * DM * 2);      // 8 MB
  __hip_bfloat16* wqkvT = (__hip_bfloat16*)alloc((size_t)3 * DM * DM * 2);    // 6 MB
  __hip_bfloat16* woT   = (__hip_bfloat16*)alloc((size_t)DM * DM * 2);        // 2 MB
  __hip_bfloat16* posb  = (__hip_bfloat16*)alloc((size_t)S_LEN * PD * 2);
  float*          pnrm  = (float*)alloc((size_t)S_LEN * 4);
  __hip_bfloat16* qb    = (__hip_bfloat16*)alloc((size_t)2 * NH * S_LEN * HD * 2); // 8 MB
  __hip_bfloat16* kb    = (__hip_bfloat16*)alloc((size_t)2 * NH * S_LEN * HD * 2);
  __hip_bfloat16* vt    = (__hip_bfloat16*)alloc((size_t)2 * NH * S_LEN * HD * 2);
  __hip_bfloat16* ob    = (__hip_bfloat16*)alloc((size_t)4096 * DM * 2);      // 8 MB
  __hip_bfloat16* dtb   = (__hip_bfloat16*)alloc((size_t)(S_LEN / 16) * S_LEN * 16 * 2); // 8 MB
  (void)ws_size;

  // prep
  int n4 = 4096 * DM / 4;
  hipLaunchKernelGGL(convx_kernel, dim3((n4 + 255) / 256), dim3(256), 0, stream,
                     x, xb, n4);
  hipLaunchKernelGGL(posprep_kernel, dim3(S_LEN), dim3(64), 0, stream,
                     pos, posb, pnrm);
  hipLaunchKernelGGL(wtrans_kernel, dim3(32, 32, 4), dim3(256), 0, stream,
                     Wq, Wk, Wv, Wo,
                     wqkvT, wqkvT + (size_t)DM * DM, wqkvT + (size_t)2 * DM * DM, woT);

  // distance-bias precompute (shared across all heads/batches)
  hipLaunchKernelGGL(dmt_kernel, dim3(S_LEN / 128, S_LEN / 64), dim3(256), 0, stream,
                     posb, pnrm, dtb);

  // fused QKV projection (M=4096, N=3072, K=1024)
  hipLaunchKernelGGL(gemm_qkv_kernel, dim3(4096 / 128, 3072 / 64), dim3(256), 0,
                     stream, xb, wqkvT, bq, bk, bv, qb, kb, vt);

  // attention
  hipLaunchKernelGGL(attn_kernel, dim3(S_LEN / 64, 2 * NH), dim3(256), 0, stream,
                     qb, kb, vt, dtb, ob);

  // output projection -> f32 d_out
  hipLaunchKernelGGL(gemm_out_kernel, dim3(4096 / 128, DM / 64), dim3(256), 0,
                     stream, ob, woT, bo, (float*)d_out);
}

// Round 6
// 291.800 us; speedup vs baseline: 2.1741x; 1.8198x over previous
//
#include <hip/hip_runtime.h>
#include <hip/hip_bf16.h>

typedef __attribute__((ext_vector_type(8))) short short8;
typedef __attribute__((ext_vector_type(4))) float f32x4;

#define S_LEN 2048
#define DM 1024
#define NH 16
#define HD 64
#define PD 64

#define LOG2E 1.4426950408889634f

#if __has_builtin(__builtin_amdgcn_exp2f)
#define EXP2F(x) __builtin_amdgcn_exp2f(x)
#else
#define EXP2F(x) exp2f(x)
#endif

static __device__ inline float bf2f(unsigned short u) {
  union { unsigned int i; float f; } c;
  c.i = ((unsigned int)u) << 16;
  return c.f;
}
static __device__ inline unsigned short f2bf(float f) {
  __hip_bfloat16 h = __float2bfloat16(f);
  return *reinterpret_cast<unsigned short*>(&h);
}

// async global->LDS, 16B per lane. LDS dest is wave-uniform base; HW writes
// lane l's 16B at base + l*16 (m104). Global src is per-lane.
static __device__ __forceinline__ void glds16(const void* g, void* l) {
  __builtin_amdgcn_global_load_lds(
      (__attribute__((address_space(1))) unsigned int*)(unsigned long long)g,
      (__attribute__((address_space(3))) unsigned int*)l, 16, 0, 0);
}

// ---------------------------------------------------------------------------
// prep kernels
// ---------------------------------------------------------------------------

__global__ void convx_kernel(const float* __restrict__ x,
                             __hip_bfloat16* __restrict__ xb, int n4) {
  int i = blockIdx.x * blockDim.x + threadIdx.x;
  if (i >= n4) return;
  const float4 v = reinterpret_cast<const float4*>(x)[i];
  union { __hip_bfloat16 h[4]; ushort4 u; } o;
  o.h[0] = __float2bfloat16(v.x);
  o.h[1] = __float2bfloat16(v.y);
  o.h[2] = __float2bfloat16(v.z);
  o.h[3] = __float2bfloat16(v.w);
  reinterpret_cast<ushort4*>(xb)[i] = o.u;
}

// one wave per position row: bf16 copy + f32 squared norm
__global__ void posprep_kernel(const float* __restrict__ pos,
                               __hip_bfloat16* __restrict__ posb,
                               float* __restrict__ pnorm) {
  int row = blockIdx.x, c = threadIdx.x;
  float v = pos[row * PD + c];
  posb[row * PD + c] = __float2bfloat16(v);
  float s = v * v;
#pragma unroll
  for (int m = 1; m < 64; m <<= 1) s += __shfl_xor(s, m);
  if (c == 0) pnorm[row] = s;
}

// W [K][N] f32 -> Wt [N][K] bf16, 32x32 LDS tile transpose; blockIdx.z picks matrix
__global__ __launch_bounds__(256) void wtrans_kernel(
    const float* __restrict__ W0, const float* __restrict__ W1,
    const float* __restrict__ W2, const float* __restrict__ W3,
    __hip_bfloat16* __restrict__ T0, __hip_bfloat16* __restrict__ T1,
    __hip_bfloat16* __restrict__ T2, __hip_bfloat16* __restrict__ T3) {
  __shared__ float tile[32][33];
  const float* W = blockIdx.z == 0 ? W0 : blockIdx.z == 1 ? W1
                 : blockIdx.z == 2 ? W2 : W3;
  __hip_bfloat16* T = blockIdx.z == 0 ? T0 : blockIdx.z == 1 ? T1
                    : blockIdx.z == 2 ? T2 : T3;
  int tx = threadIdx.x & 31, ty = threadIdx.x >> 5;  // tx 0..31, ty 0..7
  int k0 = blockIdx.x * 32, n0 = blockIdx.y * 32;
#pragma unroll
  for (int q = 0; q < 4; ++q)
    tile[ty + q * 8][tx] = W[(size_t)(k0 + ty + q * 8) * DM + n0 + tx];
  __syncthreads();
#pragma unroll
  for (int q = 0; q < 4; ++q)
    T[(size_t)(n0 + ty + q * 8) * DM + k0 + tx] =
        __float2bfloat16(tile[tx][ty + q * 8]);
}

// ---------------------------------------------------------------------------
// Distance-bias precompute: Dt[qt][j][ii] = -dist(qt*16+ii, j) * log2e (bf16),
// dist(i,i) = 0 exactly. Gram via MFMA; tiled layout matches attn's D-layout
// fragment (lane (lh,lr) reads ushort4 at [(qt*2048+j)*16 + lh*4]).
// ---------------------------------------------------------------------------
__global__ __launch_bounds__(256) void dmt_kernel(
    const __hip_bfloat16* __restrict__ posb, const float* __restrict__ pnorm,
    __hip_bfloat16* __restrict__ dtout) {
  int tid = threadIdx.x;
  int lane = tid & 63, wid = tid >> 6;
  int lr = lane & 15, lh = lane >> 4;
  int wr = wid >> 1, wc = wid & 1;
  int m0 = blockIdx.x * 128 + wr * 64;
  int n0 = blockIdx.y * 64 + wc * 32;

  f32x4 acc[4][2];
#pragma unroll
  for (int mi = 0; mi < 4; ++mi)
#pragma unroll
    for (int ni = 0; ni < 2; ++ni) acc[mi][ni] = (f32x4){0.f, 0.f, 0.f, 0.f};

  const __hip_bfloat16* Ap = posb + (size_t)(m0 + lr) * PD + lh * 8;
  const __hip_bfloat16* Bp = posb + (size_t)(n0 + lr) * PD + lh * 8;

#pragma unroll
  for (int k0 = 0; k0 < PD; k0 += 32) {
    short8 a[4], b[2];
#pragma unroll
    for (int mi = 0; mi < 4; ++mi)
      a[mi] = *reinterpret_cast<const short8*>(Ap + (size_t)mi * 16 * PD + k0);
#pragma unroll
    for (int ni = 0; ni < 2; ++ni)
      b[ni] = *reinterpret_cast<const short8*>(Bp + (size_t)ni * 16 * PD + k0);
#pragma unroll
    for (int mi = 0; mi < 4; ++mi)
#pragma unroll
      for (int ni = 0; ni < 2; ++ni)
        acc[mi][ni] = __builtin_amdgcn_mfma_f32_16x16x32_bf16(
            a[mi], b[ni], acc[mi][ni], 0, 0, 0);
  }

#pragma unroll
  for (int mi = 0; mi < 4; ++mi) {
    float nim[4];
#pragma unroll
    for (int r = 0; r < 4; ++r) nim[r] = pnorm[m0 + mi * 16 + lh * 4 + r];
#pragma unroll
    for (int ni = 0; ni < 2; ++ni) {
      int j = n0 + ni * 16 + lr;
      float nj = pnorm[j];
      ushort4 o;
      unsigned short* op = &o.x;
#pragma unroll
      for (int r = 0; r < 4; ++r) {
        int i = m0 + mi * 16 + lh * 4 + r;
        float d2 = nim[r] + nj - 2.f * acc[mi][ni][r];
        float dist = (i == j) ? 0.f : sqrtf(fmaxf(d2, 0.f));
        op[r] = f2bf(-dist * LOG2E);
      }
      int qt = (m0 + mi * 16) >> 4;
      *reinterpret_cast<ushort4*>(dtout + ((size_t)qt * S_LEN + j) * 16 + lh * 4) = o;
    }
  }
}

// ---------------------------------------------------------------------------
// Fused QKV projection, staged (m97-style): 128x128 tile, BK=32, 4 waves 2x2,
// each wave 64x64 (4x4 fragments). global_load_lds double-buffer, 2-phase loop.
// LDS chunk layout: chunk g (16 rows x 32 k) at g*1024B, lane l's 16B at
// l*16 holds row (g*16 + (l&15)), k-cols (l>>4)*8..+8  -> fragment read is
// ds_read_b128 at chunkbase + lane*16 (identical addr math as staging).
// n>>10 routes to Q [B,H,S,64], K [B,H,S,64], or V^T [B,H,64,S].
// ---------------------------------------------------------------------------
__global__ __launch_bounds__(256) void gemm_qkv_kernel(
    const __hip_bfloat16* __restrict__ A, const __hip_bfloat16* __restrict__ Bt,
    const float* __restrict__ bq, const float* __restrict__ bk,
    const float* __restrict__ bv, __hip_bfloat16* __restrict__ qb,
    __hip_bfloat16* __restrict__ kb, __hip_bfloat16* __restrict__ vt) {
  const int K = DM;
  __shared__ __hip_bfloat16 abuf[2][4096];  // 2 x 8KB (128 rows x 32 k)
  __shared__ __hip_bfloat16 bbuf[2][4096];
  int tid = threadIdx.x;
  int lane = tid & 63, w = tid >> 6;
  int lr = lane & 15, lh = lane >> 4;
  int wr = w >> 1, wc = w & 1;
  int m0 = blockIdx.x * 128;
  int n0 = blockIdx.y * 128;

  f32x4 acc[4][4];
#pragma unroll
  for (int mi = 0; mi < 4; ++mi)
#pragma unroll
    for (int ni = 0; ni < 4; ++ni) acc[mi][ni] = (f32x4){0.f, 0.f, 0.f, 0.f};

  // per-lane global bases for staging
  const __hip_bfloat16* Ag = A + (size_t)(m0 + lr) * K + lh * 8;
  const __hip_bfloat16* Bg = Bt + (size_t)(n0 + lr) * K + lh * 8;

  auto STAGE = [&](int nb, int k0) {
#pragma unroll
    for (int q = 0; q < 2; ++q) {
      int g = w * 2 + q;
      glds16(Ag + (size_t)(g * 16) * K + k0, &abuf[nb][g * 512]);
      glds16(Bg + (size_t)(g * 16) * K + k0, &bbuf[nb][g * 512]);
    }
  };

  STAGE(0, 0);
  __syncthreads();

  const int NT = K / 32;
  for (int t = 0; t < NT; ++t) {
    int cb = t & 1;
    if (t + 1 < NT) STAGE(cb ^ 1, (t + 1) * 32);
    short8 a[4], b[4];
#pragma unroll
    for (int mi = 0; mi < 4; ++mi)
      a[mi] = *reinterpret_cast<const short8*>(&abuf[cb][(wr * 4 + mi) * 512 + lane * 8]);
#pragma unroll
    for (int ni = 0; ni < 4; ++ni)
      b[ni] = *reinterpret_cast<const short8*>(&bbuf[cb][(wc * 4 + ni) * 512 + lane * 8]);
#pragma unroll
    for (int mi = 0; mi < 4; ++mi)
#pragma unroll
      for (int ni = 0; ni < 4; ++ni)
        acc[mi][ni] = __builtin_amdgcn_mfma_f32_16x16x32_bf16(
            a[mi], b[ni], acc[mi][ni], 0, 0, 0);
    __syncthreads();  // drains vmcnt+lgkmcnt: staged tile ready, reads done
  }

#pragma unroll
  for (int mi = 0; mi < 4; ++mi)
#pragma unroll
    for (int ni = 0; ni < 4; ++ni)
#pragma unroll
      for (int r = 0; r < 4; ++r) {
        int row = m0 + wr * 64 + mi * 16 + lh * 4 + r;
        int col = n0 + wc * 64 + ni * 16 + lr;
        int which = col >> 10, within = col & 1023;
        int bb = row >> 11, s = row & 2047;
        int h = within >> 6, d = within & 63;
        const float* bias = which == 0 ? bq : which == 1 ? bk : bv;
        float v = acc[mi][ni][r] + bias[within];
        __hip_bfloat16 hv = __float2bfloat16(v);
        if (which == 0)
          qb[((size_t)(bb * NH + h) * S_LEN + s) * HD + d] = hv;
        else if (which == 1)
          kb[((size_t)(bb * NH + h) * S_LEN + s) * HD + d] = hv;
        else
          vt[((size_t)(bb * NH + h) * HD + d) * S_LEN + s] = hv;
      }
}

// ---------------------------------------------------------------------------
// Output projection: f32 out row-major, direct-global fragments (small GEMM).
// ---------------------------------------------------------------------------
__global__ __launch_bounds__(256) void gemm_out_kernel(
    const __hip_bfloat16* __restrict__ A, const __hip_bfloat16* __restrict__ Bt,
    const float* __restrict__ bias, float* __restrict__ out) {
  const int K = DM, N = DM;
  int tid = threadIdx.x;
  int lane = tid & 63, wid = tid >> 6;
  int lr = lane & 15, lh = lane >> 4;
  int wr = wid >> 1, wc = wid & 1;
  int m0 = blockIdx.x * 128 + wr * 64;
  int n0 = blockIdx.y * 64 + wc * 32;

  f32x4 acc[4][2];
#pragma unroll
  for (int mi = 0; mi < 4; ++mi)
#pragma unroll
    for (int ni = 0; ni < 2; ++ni) acc[mi][ni] = (f32x4){0.f, 0.f, 0.f, 0.f};

  const __hip_bfloat16* Ap = A + (size_t)(m0 + lr) * K + lh * 8;
  const __hip_bfloat16* Bp = Bt + (size_t)(n0 + lr) * K + lh * 8;

  for (int k0 = 0; k0 < K; k0 += 32) {
    short8 a[4], b[2];
#pragma unroll
    for (int mi = 0; mi < 4; ++mi)
      a[mi] = *reinterpret_cast<const short8*>(Ap + (size_t)mi * 16 * K + k0);
#pragma unroll
    for (int ni = 0; ni < 2; ++ni)
      b[ni] = *reinterpret_cast<const short8*>(Bp + (size_t)ni * 16 * K + k0);
#pragma unroll
    for (int mi = 0; mi < 4; ++mi)
#pragma unroll
      for (int ni = 0; ni < 2; ++ni)
        acc[mi][ni] = __builtin_amdgcn_mfma_f32_16x16x32_bf16(
            a[mi], b[ni], acc[mi][ni], 0, 0, 0);
  }

#pragma unroll
  for (int mi = 0; mi < 4; ++mi)
#pragma unroll
    for (int ni = 0; ni < 2; ++ni)
#pragma unroll
      for (int r = 0; r < 4; ++r) {
        int row = m0 + mi * 16 + lh * 4 + r;
        int col = n0 + ni * 16 + lr;
        out[(size_t)row * N + col] = acc[mi][ni][r] + bias[col];
      }
}

// ---------------------------------------------------------------------------
// Flash attention, 2-phase pipelined K/V LDS staging.
//   score2(i,j) = (q_i.k_j) * (0.125*log2e) + Dt(i,j)   [Dt = -dist*log2e]
//   p = exp2(score2); denom via ones-MFMA.
// Block = 4 waves, 64 q-rows; j-chunk = 64. All 4 waves share the staged
// K/V chunk (4x fewer global loads). STAGE(t+1) issued before compute(t);
// one __syncthreads (full vmcnt drain) per chunk.
// LDS: K 2x8KB + V 2x8KB + P 8KB = 40KB -> 4 blocks/CU = 160KB exact.
// ---------------------------------------------------------------------------
__global__ __launch_bounds__(256) void attn_kernel(
    const __hip_bfloat16* __restrict__ qb, const __hip_bfloat16* __restrict__ kb,
    const __hip_bfloat16* __restrict__ vt, const __hip_bfloat16* __restrict__ dt,
    __hip_bfloat16* __restrict__ ob) {
  __shared__ __hip_bfloat16 kbuf[2][4096];  // chunk (jt*2+kk)*512 + lane*8
  __shared__ __hip_bfloat16 vbuf[2][4096];  // chunk (n*2+p2)*512 + lane*8
  __shared__ __hip_bfloat16 plds[4][16 * 64];
  int tid = threadIdx.x;
  int lane = tid & 63, w = tid >> 6;
  int lr = lane & 15, lh = lane >> 4;
  int bh = blockIdx.y;
  int b = bh >> 4, h = bh & 15;
  int s0 = blockIdx.x * 64 + w * 16;
  int qt = s0 >> 4;

  const __hip_bfloat16* qh = qb + (size_t)bh * S_LEN * HD;
  const __hip_bfloat16* kh = kb + (size_t)bh * S_LEN * HD;
  const __hip_bfloat16* vh = vt + (size_t)bh * HD * S_LEN;

  short8 qf0 = *reinterpret_cast<const short8*>(qh + (size_t)(s0 + lr) * HD + lh * 8);
  short8 qf1 = *reinterpret_cast<const short8*>(qh + (size_t)(s0 + lr) * HD + 32 + lh * 8);

  f32x4 accO[4];
#pragma unroll
  for (int n = 0; n < 4; ++n) accO[n] = (f32x4){0.f, 0.f, 0.f, 0.f};
  f32x4 lacc = (f32x4){0.f, 0.f, 0.f, 0.f};

  short8 ones;
#pragma unroll
  for (int e = 0; e < 8; ++e) ones[e] = (short)0x3F80;  // bf16 1.0

  const f32x4 z4 = (f32x4){0.f, 0.f, 0.f, 0.f};
  const float C2 = 0.125f * LOG2E;

  // per-lane staging source bases; wave w stages K row-group w, V d-group w
  const __hip_bfloat16* kstg = kh + (size_t)(w * 16 + lr) * HD + lh * 8;
  const __hip_bfloat16* vstg = vh + (size_t)(w * 16 + lr) * S_LEN + lh * 8;

  auto STAGE = [&](int nb, int j0n) {
#pragma unroll
    for (int kk = 0; kk < 2; ++kk)
      glds16(kstg + (size_t)j0n * HD + kk * 32, &kbuf[nb][(w * 2 + kk) * 512]);
#pragma unroll
    for (int jj = 0; jj < 2; ++jj)
      glds16(vstg + j0n + jj * 32, &vbuf[nb][(w * 2 + jj) * 512]);
  };

  STAGE(0, 0);
  __syncthreads();

  const int NT = S_LEN / 64;
  for (int t = 0; t < NT; ++t) {
    int cb = t & 1;
    int j0 = t * 64;
    if (t + 1 < NT) STAGE(cb ^ 1, j0 + 64);

    // Dt loads for this chunk (independent of QK MFMAs -> latency hidden)
    ushort4 dv[4];
#pragma unroll
    for (int jt = 0; jt < 4; ++jt)
      dv[jt] = *reinterpret_cast<const ushort4*>(
          dt + ((size_t)qt * S_LEN + j0 + jt * 16 + lr) * 16 + lh * 4);

#pragma unroll
    for (int jt = 0; jt < 4; ++jt) {
      short8 kf0 = *reinterpret_cast<const short8*>(&kbuf[cb][(jt * 2 + 0) * 512 + lane * 8]);
      short8 kf1 = *reinterpret_cast<const short8*>(&kbuf[cb][(jt * 2 + 1) * 512 + lane * 8]);
      f32x4 s4 = __builtin_amdgcn_mfma_f32_16x16x32_bf16(qf0, kf0, z4, 0, 0, 0);
      s4 = __builtin_amdgcn_mfma_f32_16x16x32_bf16(qf1, kf1, s4, 0, 0, 0);
      const unsigned short* dp = &dv[jt].x;
#pragma unroll
      for (int r = 0; r < 4; ++r) {
        float score2 = s4[r] * C2 + bf2f(dp[r]);
        float p = EXP2F(score2);
        int row = lh * 4 + r;
        int c = jt * 16 + lr;
        // XOR-swizzled store: 8-col block index ^= (row & 7)
        int idx = row * 64 + (((c >> 3) ^ (row & 7)) << 3) + (c & 7);
        plds[w][idx] = __float2bfloat16(p);
      }
    }
    // per-wave LDS tile, same-wave RAW: compiler inserts lgkmcnt wait
#pragma unroll
    for (int p2 = 0; p2 < 2; ++p2) {
      short8 pfrag = *reinterpret_cast<const short8*>(
          &plds[w][lr * 64 + ((((p2 * 4 + lh)) ^ (lr & 7)) << 3)]);
      lacc = __builtin_amdgcn_mfma_f32_16x16x32_bf16(pfrag, ones, lacc, 0, 0, 0);
#pragma unroll
      for (int n = 0; n < 4; ++n) {
        short8 vf = *reinterpret_cast<const short8*>(
            &vbuf[cb][(n * 2 + p2) * 512 + lane * 8]);
        accO[n] = __builtin_amdgcn_mfma_f32_16x16x32_bf16(pfrag, vf, accO[n], 0, 0, 0);
      }
    }
    __syncthreads();  // staged next chunk ready; all waves done with cb
  }

  float inv[4];
#pragma unroll
  for (int r = 0; r < 4; ++r) inv[r] = 1.f / lacc[r];
#pragma unroll
  for (int n = 0; n < 4; ++n)
#pragma unroll
    for (int r = 0; r < 4; ++r) {
      int s = s0 + lh * 4 + r;
      ob[((size_t)(b * S_LEN) + s) * DM + h * HD + n * 16 + lr] =
          __float2bfloat16(accO[n][r] * inv[r]);
    }
}

// ---------------------------------------------------------------------------
// launch
// ---------------------------------------------------------------------------
extern "C" void kernel_launch(void* const* d_in, const int* in_sizes, int n_in,
                              void* d_out, int out_size, void* d_ws, size_t ws_size,
                              hipStream_t stream) {
  const float* x   = (const float*)d_in[0];
  const float* pos = (const float*)d_in[1];
  const float* Wq  = (const float*)d_in[2];
  const float* bq  = (const float*)d_in[3];
  const float* Wk  = (const float*)d_in[4];
  const float* bk  = (const float*)d_in[5];
  const float* Wv  = (const float*)d_in[6];
  const float* bv  = (const float*)d_in[7];
  const float* Wo  = (const float*)d_in[8];
  const float* bo  = (const float*)d_in[9];

  char* ws = (char*)d_ws;
  size_t off = 0;
  auto alloc = [&](size_t bytes) {
    char* p = ws + off;
    off += (bytes + 255) & ~(size_t)255;
    return p;
  };
  __hip_bfloat16* xb    = (__hip_bfloat16*)alloc((size_t)4096 * DM * 2);      // 8 MB
  __hip_bfloat16* wqkvT = (__hip_bfloat16*)alloc((size_t)3 * DM * DM * 2);    // 6 MB
  __hip_bfloat16* woT   = (__hip_bfloat16*)alloc((size_t)DM * DM * 2);        // 2 MB
  __hip_bfloat16* posb  = (__hip_bfloat16*)alloc((size_t)S_LEN * PD * 2);
  float*          pnrm  = (float*)alloc((size_t)S_LEN * 4);
  __hip_bfloat16* qb    = (__hip_bfloat16*)alloc((size_t)2 * NH * S_LEN * HD * 2); // 8 MB
  __hip_bfloat16* kb    = (__hip_bfloat16*)alloc((size_t)2 * NH * S_LEN * HD * 2);
  __hip_bfloat16* vt    = (__hip_bfloat16*)alloc((size_t)2 * NH * S_LEN * HD * 2);
  __hip_bfloat16* ob    = (__hip_bfloat16*)alloc((size_t)4096 * DM * 2);      // 8 MB
  __hip_bfloat16* dtb   = (__hip_bfloat16*)alloc((size_t)(S_LEN / 16) * S_LEN * 16 * 2); // 8 MB
  (void)ws_size;

  // prep
  int n4 = 4096 * DM / 4;
  hipLaunchKernelGGL(convx_kernel, dim3((n4 + 255) / 256), dim3(256), 0, stream,
                     x, xb, n4);
  hipLaunchKernelGGL(posprep_kernel, dim3(S_LEN), dim3(64), 0, stream,
                     pos, posb, pnrm);
  hipLaunchKernelGGL(wtrans_kernel, dim3(32, 32, 4), dim3(256), 0, stream,
                     Wq, Wk, Wv, Wo,
                     wqkvT, wqkvT + (size_t)DM * DM, wqkvT + (size_t)2 * DM * DM, woT);

  // distance-bias precompute (shared across all heads/batches)
  hipLaunchKernelGGL(dmt_kernel, dim3(S_LEN / 128, S_LEN / 64), dim3(256), 0, stream,
                     posb, pnrm, dtb);

  // fused QKV projection (M=4096, N=3072, K=1024), staged
  hipLaunchKernelGGL(gemm_qkv_kernel, dim3(4096 / 128, 3072 / 128), dim3(256), 0,
                     stream, xb, wqkvT, bq, bk, bv, qb, kb, vt);

  // attention
  hipLaunchKernelGGL(attn_kernel, dim3(S_LEN / 64, 2 * NH), dim3(256), 0, stream,
                     qb, kb, vt, dtb, ob);

  // output projection -> f32 d_out
  hipLaunchKernelGGL(gemm_out_kernel, dim3(4096 / 128, DM / 64), dim3(256), 0,
                     stream, ob, woT, bo, (float*)d_out);
}